// Round 2
// baseline (187.815 us; speedup 1.0000x reference)
//
#include <hip/hip_runtime.h>
#include <hip/hip_bf16.h>

// AdjustedNonLocalBlock: 3x conv1x1 -> attention(S=4096,D=64,B=4) -> conv1x1 + residual.
// I/O is fp32 (reference setup_inputs is jnp.float32; harness contract: float32 -> float*).
// Internals in bf16 for MFMA.
//
// Pipeline (4 launches):
//   1. conv_in:   theta(x1)->Q[b][n][64] (scaled by log2e), phi(x0)->K[b][n][64],
//                 g(x0)->Vt[b][64][n]   (all bf16 in ws)
//   2. attn:      S^T = K*Q^T via mfma_16x16x32_bf16; P=2^S packed b64 into LDS;
//                 O += P*V; no-max softmax (logits bounded); ksplit=4 partials
//   3. combine:   y = sum_ks(Opart)/sum_ks(Lp) -> Y bf16
//   4. conv_out:  out = W*y + Wb + x0   (fp32 in/out)

typedef unsigned int   u32;
typedef unsigned short u16;
typedef __attribute__((ext_vector_type(8))) short short8;   // 8x bf16 = 4 VGPR (MFMA A/B frag)
typedef __attribute__((ext_vector_type(4))) float f32x4;    // MFMA C/D frag

#define LOG2E 1.4426950408889634f

__device__ __forceinline__ float b2f(u16 v) {
  union { u32 u; float f; } x; x.u = ((u32)v) << 16; return x.f;
}
__device__ __forceinline__ u16 f2b(float f) {   // round-to-nearest
  u32 u = __float_as_uint(f);
  return (u16)((u + 0x8000u) >> 16);
}

// ---------------- workspace layout (bytes) ----------------
// Q    [4][4096][64]  bf16 @ 0      (2 MB)
// K    [4][4096][64]  bf16 @ 2 MB   (2 MB)
// Vt   [4][64][4096]  bf16 @ 4 MB   (2 MB)
// Y    [4][4096][64]  bf16 @ 6 MB   (2 MB)
// Opart[4ks][4][4096][64] bf16 @ 8 MB (8 MB)
// Lp   [4ks][4][4096] f32  @ 16 MB  (256 KB)   -> total ~16.25 MB

// grid (16 n-tiles, 3 convs * 2 o-halves, 4 batches), block 256. One thread = one n, 32 outputs.
// Weight indices are block-uniform -> scalar loads; inner loop is v_fmac with sgpr operand.
__global__ __launch_bounds__(256) void conv_in_kernel(
    const float* __restrict__ x0, const float* __restrict__ x1,
    const float* __restrict__ tw, const float* __restrict__ tb,
    const float* __restrict__ pw, const float* __restrict__ pb,
    const float* __restrict__ gw, const float* __restrict__ gb,
    u16* __restrict__ Q, u16* __restrict__ K, u16* __restrict__ Vt)
{
  const int n    = blockIdx.x * 256 + threadIdx.x;
  const int conv = blockIdx.y >> 1;   // 0=theta(x1), 1=phi(x0), 2=g(x0)
  const int oh   = blockIdx.y & 1;    // output half (32 channels)
  const int b    = blockIdx.z;

  const float* src  = (conv == 0) ? x1 : x0;
  const float* w    = ((conv == 0) ? tw : (conv == 1) ? pw : gw) + (oh * 32) * 128;
  const float* bias = ((conv == 0) ? tb : (conv == 1) ? pb : gb) + oh * 32;
  const float scale = (conv == 0) ? LOG2E : 1.f;   // fold log2(e) into theta so exp == exp2

  float acc[32];
  #pragma unroll
  for (int oo = 0; oo < 32; ++oo) acc[oo] = bias[oo];

  const float* xcol = src + (size_t)b * 128 * 4096 + n;
  #pragma unroll 4
  for (int c = 0; c < 128; ++c) {
    float xv = xcol[(size_t)c * 4096];   // coalesced over n
    #pragma unroll
    for (int oo = 0; oo < 32; ++oo)
      acc[oo] = fmaf(w[oo * 128 + c], xv, acc[oo]);
  }

  if (conv < 2) {
    // row-major [b][n][64] bf16, vectorized 4x16B store
    u16* dst = (conv == 0 ? Q : K) + ((size_t)b * 4096 + n) * 64 + oh * 32;
    u32 wd[16];
    #pragma unroll
    for (int i = 0; i < 16; ++i)
      wd[i] = (u32)f2b(acc[2 * i] * scale) | ((u32)f2b(acc[2 * i + 1] * scale) << 16);
    ((uint4*)dst)[0] = make_uint4(wd[0],  wd[1],  wd[2],  wd[3]);
    ((uint4*)dst)[1] = make_uint4(wd[4],  wd[5],  wd[6],  wd[7]);
    ((uint4*)dst)[2] = make_uint4(wd[8],  wd[9],  wd[10], wd[11]);
    ((uint4*)dst)[3] = make_uint4(wd[12], wd[13], wd[14], wd[15]);
  } else {
    // transposed [b][64][4096] (natural V^T for the PV B-fragment), coalesced over n
    u16* dst = Vt + (size_t)b * 64 * 4096 + n;
    #pragma unroll
    for (int oo = 0; oo < 32; ++oo)
      dst[(size_t)(oh * 32 + oo) * 4096] = f2b(acc[oo]);
  }
}

// grid (16 q-tiles of 256, 4 batches, 4 ksplits), block 256 = 4 waves; wave owns 64 q-rows.
// S^T = K*Q^T so P exits with 4 consecutive k per lane -> b64-packed LDS writes; P re-read
// as A-frag (b128) for O = P*V. No softmax max needed (logits bounded); partials addable.
__global__ __launch_bounds__(256) void attn_kernel(
    const u16* __restrict__ Q, const u16* __restrict__ K,
    const u16* __restrict__ Vt, u16* __restrict__ Opart,
    float* __restrict__ Lp)
{
  const int qt = blockIdx.x, b = blockIdx.y, ks = blockIdx.z;
  const int tid  = threadIdx.x;
  const int wave = tid >> 6;
  const int lane = tid & 63;
  const int quad = lane >> 4;
  const int l15  = lane & 15;

  __shared__ __align__(16) u16 P_lds[4][64][72];   // per-wave [q][k], +8 pad
  u16* pw = &P_lds[wave][0][0];

  const int q0 = qt * 256 + wave * 64;
  const u16* Qb = Q  + (size_t)b * 4096 * 64;
  const u16* Kb = K  + (size_t)b * 4096 * 64;
  const u16* Vb = Vt + (size_t)b * 64 * 4096;

  // Q fragments (B operand of S^T): qf[nt][kk] = Q[q0+nt*16+l15][kk*32+quad*8 .. +7]
  short8 qf[4][2];
  #pragma unroll
  for (int nt = 0; nt < 4; ++nt) {
    const u16* qp = Qb + (size_t)(q0 + nt * 16 + l15) * 64 + quad * 8;
    qf[nt][0] = *(const short8*)qp;
    qf[nt][1] = *(const short8*)(qp + 32);
  }

  f32x4 oacc[4][4];   // [mq][nd]
  #pragma unroll
  for (int i = 0; i < 4; ++i)
    #pragma unroll
    for (int j = 0; j < 4; ++j)
      oacc[i][j] = (f32x4){0.f, 0.f, 0.f, 0.f};
  float lsum[4] = {0.f, 0.f, 0.f, 0.f};   // per lane: q = nt*16+l15, this quad's k subset

  const int kbase = ks * 1024;

  // preload first K fragments (A operand of S^T)
  short8 kf[4][2];
  #pragma unroll
  for (int mt = 0; mt < 4; ++mt) {
    const u16* kp = Kb + (size_t)(kbase + mt * 16 + l15) * 64 + quad * 8;
    kf[mt][0] = *(const short8*)kp;
    kf[mt][1] = *(const short8*)(kp + 32);
  }

  for (int kt = 0; kt < 16; ++kt) {
    const int k0 = kbase + kt * 64;

    // V fragments for this k-tile, issued early (latency covered by S MFMAs)
    short8 vf[4][2];
    #pragma unroll
    for (int nd = 0; nd < 4; ++nd) {
      const u16* vp = Vb + (size_t)(nd * 16 + l15) * 4096 + k0 + quad * 8;
      vf[nd][0] = *(const short8*)vp;
      vf[nd][1] = *(const short8*)(vp + 32);
    }

    // S^T tiles, exp2, pack, write P[q][k] to LDS (b64: 4 consecutive k per lane)
    #pragma unroll
    for (int mt = 0; mt < 4; ++mt) {
      #pragma unroll
      for (int nt = 0; nt < 4; ++nt) {
        f32x4 s = {0.f, 0.f, 0.f, 0.f};
        s = __builtin_amdgcn_mfma_f32_16x16x32_bf16(kf[mt][0], qf[nt][0], s, 0, 0, 0);
        s = __builtin_amdgcn_mfma_f32_16x16x32_bf16(kf[mt][1], qf[nt][1], s, 0, 0, 0);
        float p0 = exp2f(s[0]), p1 = exp2f(s[1]), p2 = exp2f(s[2]), p3 = exp2f(s[3]);
        lsum[nt] += (p0 + p1) + (p2 + p3);
        u32 u0 = __float_as_uint(p0) + 0x8000u;
        u32 u1 = __float_as_uint(p1) + 0x8000u;
        u32 u2 = __float_as_uint(p2) + 0x8000u;
        u32 u3 = __float_as_uint(p3) + 0x8000u;
        uint2 pk;
        pk.x = __builtin_amdgcn_perm(u1, u0, 0x07060302u);  // [b16(p1):b16(p0)]
        pk.y = __builtin_amdgcn_perm(u3, u2, 0x07060302u);
        *(uint2*)(pw + (nt * 16 + l15) * 72 + mt * 16 + quad * 4) = pk;
      }
    }

    // prefetch next K fragments (in flight across the PV phase)
    if (kt < 15) {
      #pragma unroll
      for (int mt = 0; mt < 4; ++mt) {
        const u16* kp = Kb + (size_t)(k0 + 64 + mt * 16 + l15) * 64 + quad * 8;
        kf[mt][0] = *(const short8*)kp;
        kf[mt][1] = *(const short8*)(kp + 32);
      }
    }

    // O += P*V : A-frag of P from LDS (b128), B-frag of V from registers
    #pragma unroll
    for (int mq = 0; mq < 4; ++mq) {
      const u16* pr = pw + (mq * 16 + l15) * 72 + quad * 8;
      short8 pa0 = *(const short8*)pr;
      short8 pa1 = *(const short8*)(pr + 32);
      #pragma unroll
      for (int nd = 0; nd < 4; ++nd) {
        oacc[mq][nd] = __builtin_amdgcn_mfma_f32_16x16x32_bf16(pa0, vf[nd][0], oacc[mq][nd], 0, 0, 0);
        oacc[mq][nd] = __builtin_amdgcn_mfma_f32_16x16x32_bf16(pa1, vf[nd][1], oacc[mq][nd], 0, 0, 0);
      }
    }
  }

  // complete row sums across the 4 quads (each quad held a disjoint k subset)
  #pragma unroll
  for (int nt = 0; nt < 4; ++nt) {
    float v = lsum[nt];
    v += __shfl_xor(v, 16, 64);
    v += __shfl_xor(v, 32, 64);
    lsum[nt] = v;
  }
  float* LpB = Lp + ((size_t)ks * 4 + b) * 4096;
  if (quad == 0) {
    #pragma unroll
    for (int nt = 0; nt < 4; ++nt)
      LpB[q0 + nt * 16 + l15] = lsum[nt];
  }

  // unnormalized partial O, bf16: O[q = q0+mq*16+quad*4+r][d = nd*16+l15]
  u16* Ob = Opart + ((size_t)ks * 4 + b) * 4096 * 64;
  #pragma unroll
  for (int mq = 0; mq < 4; ++mq)
    #pragma unroll
    for (int nd = 0; nd < 4; ++nd)
      #pragma unroll
      for (int r = 0; r < 4; ++r) {
        int q = q0 + mq * 16 + quad * 4 + r;
        Ob[(size_t)q * 64 + nd * 16 + l15] = f2b(oacc[mq][nd][r]);
      }
}

__global__ __launch_bounds__(256) void combine_kernel(
    const u16* __restrict__ Opart, const float* __restrict__ Lp,
    u16* __restrict__ Y)
{
  int idx = blockIdx.x * 256 + threadIdx.x;   // over 4*4096*64
  int d  = idx & 63;
  int bq = idx >> 6;
  float acc = 0.f, l = 0.f;
  #pragma unroll
  for (int ks = 0; ks < 4; ++ks) {
    acc += b2f(Opart[((size_t)ks * 4 * 4096 + bq) * 64 + d]);
    l   += Lp[(size_t)ks * 4 * 4096 + bq];
  }
  Y[(size_t)bq * 64 + d] = f2b(acc / l);
}

// grid (16 n-tiles, 4 o-quarters, 4 batches). out = W*y + Wb + x0 (fp32).
__global__ __launch_bounds__(256) void conv_out_kernel(
    const u16* __restrict__ Y, const float* __restrict__ Wf,
    const float* __restrict__ Wbf, const float* __restrict__ x0,
    float* __restrict__ out)
{
  const int n  = blockIdx.x * 256 + threadIdx.x;
  const int oq = blockIdx.y;
  const int b  = blockIdx.z;

  uint4 yraw[8];
  const u16* yrow = Y + ((size_t)b * 4096 + n) * 64;
  #pragma unroll
  for (int v = 0; v < 8; ++v) yraw[v] = ((const uint4*)yrow)[v];
  const u16* yu = (const u16*)yraw;

  const float* wq = Wf + (oq * 32) * 64;   // W_w[o][ci]
  float acc[32];
  #pragma unroll
  for (int oo = 0; oo < 32; ++oo) acc[oo] = Wbf[oq * 32 + oo];

  #pragma unroll 4
  for (int ci = 0; ci < 64; ++ci) {
    float yv = b2f(yu[ci]);
    #pragma unroll
    for (int oo = 0; oo < 32; ++oo)
      acc[oo] = fmaf(wq[oo * 64 + ci], yv, acc[oo]);
  }

  #pragma unroll
  for (int oo = 0; oo < 32; ++oo) {
    int o = oq * 32 + oo;
    size_t idx = ((size_t)(b * 128 + o)) * 4096 + n;
    out[idx] = acc[oo] + x0[idx];
  }
}

extern "C" void kernel_launch(void* const* d_in, const int* in_sizes, int n_in,
                              void* d_out, int out_size, void* d_ws, size_t ws_size,
                              hipStream_t stream) {
  const float* x0 = (const float*)d_in[0];
  const float* x1 = (const float*)d_in[1];
  const float* gw = (const float*)d_in[2];
  const float* gb = (const float*)d_in[3];
  const float* tw = (const float*)d_in[4];
  const float* tb = (const float*)d_in[5];
  const float* pw = (const float*)d_in[6];
  const float* pb = (const float*)d_in[7];
  const float* Ww = (const float*)d_in[8];
  const float* Wb = (const float*)d_in[9];
  float* out = (float*)d_out;

  char* ws = (char*)d_ws;
  u16*   Qw    = (u16*)(ws + 0);
  u16*   Kw    = (u16*)(ws + (2u << 20));
  u16*   Vtw   = (u16*)(ws + (4u << 20));
  u16*   Yw    = (u16*)(ws + (6u << 20));
  u16*   Opart = (u16*)(ws + (8u << 20));
  float* Lp    = (float*)(ws + (16u << 20));   // ~16.25 MB total

  conv_in_kernel<<<dim3(16, 6, 4), dim3(256), 0, stream>>>(
      x0, x1, tw, tb, pw, pb, gw, gb, Qw, Kw, Vtw);

  attn_kernel<<<dim3(16, 4, 4), dim3(256), 0, stream>>>(Qw, Kw, Vtw, Opart, Lp);

  combine_kernel<<<dim3(4096), dim3(256), 0, stream>>>(Opart, Lp, Yw);

  conv_out_kernel<<<dim3(16, 4, 4), dim3(256), 0, stream>>>(
      Yw, Ww, Wb, x0, out);
}